// Round 11
// baseline (86.236 us; speedup 1.0000x reference)
//
#include <hip/hip_runtime.h>
#include <hip/hip_bf16.h>

#define BB 8
#define NN 256
#define CC 32
#define LL 4
#define BN (BB*NN)          // 2048
#define LC (LL*CC)          // 128

typedef short short8 __attribute__((ext_vector_type(8)));
typedef float f32x4 __attribute__((ext_vector_type(4)));

union U8 { short8 s; unsigned u[4]; };

__device__ inline unsigned pkbf(float a, float b){
    __hip_bfloat162 h = __float22bfloat162_rn(make_float2(a, b));
    union { __hip_bfloat162 h2; unsigned u; } cv; cv.h2 = h; return cv.u;
}

// ---------------- Kernel 0: init — zero pooled accumulators, pack Rw2/Wv ----------------
__global__ __launch_bounds__(256) void so3_init(
    const float* __restrict__ Rw2,    // (32,128)
    const float* __restrict__ Wv,     // (L,4,32)
    float* __restrict__ pmaxg,        // (B,128) -> 0
    float* __restrict__ psumg,        // (B,128) -> 0
    short* __restrict__ RW2bf,        // (128,32) bf16 [col][k]
    float* __restrict__ WvT)          // (128,4)  [col][d]
{
    const int t = threadIdx.x;
    #pragma unroll
    for (int rr = 0; rr < 4; ++rr) {
        pmaxg[rr*256 + t] = 0.f;
        psumg[rr*256 + t] = 0.f;
    }
    {
        const int col = t >> 1, kh = (t & 1) * 16;
        unsigned uu[8];
        #pragma unroll
        for (int q = 0; q < 8; ++q)
            uu[q] = pkbf(Rw2[(kh + 2*q)*LC + col], Rw2[(kh + 2*q + 1)*LC + col]);
        *(uint4*)&RW2bf[col*32 + kh]     = make_uint4(uu[0], uu[1], uu[2], uu[3]);
        *(uint4*)&RW2bf[col*32 + kh + 8] = make_uint4(uu[4], uu[5], uu[6], uu[7]);
    }
    if (t < 128) {
        const int l = t >> 5, c = t & 31;
        float4 o;
        o.x = Wv[l*128 +       c];
        o.y = Wv[l*128 +  32 + c];
        o.z = Wv[l*128 +  64 + c];
        o.w = Wv[l*128 +  96 + c];
        *(float4*)&WvT[t*4] = o;
    }
}

// ---------------- Kernel B: fused per-(b,i), 4 waves (col-half x j-half) ----------------
__global__ __launch_bounds__(256, 4) void so3_main(
    const float* __restrict__ xg,     // (B,N,4)
    const float* __restrict__ Wq,     // (4,32)
    const float* __restrict__ Wk,     // (4,32)
    const float* __restrict__ Rw1,    // (32)
    const float* __restrict__ Rb1,    // (32)
    const short* __restrict__ RW2bf,  // (128,32) bf16
    const float* __restrict__ Rb2,    // (128)
    const float* __restrict__ WvT,    // (128,4)
    float* __restrict__ pmaxg,        // (B,128)
    float* __restrict__ psumg)        // (B,128)
{
    const int tid = threadIdx.x;          // 0..255
    const int bi = blockIdx.x;            // b*N + i
    const int b = bi >> 8;
    const int i = bi & 255;
    const int rowbase = b * NN;
    const int lane = tid & 63;
    const int w = tid >> 6;               // wave 0..3
    const int wcol = w & 1;               // column half
    const int jhalf = w >> 1;             // j half
    const int n = lane & 15;
    const int g = lane >> 4;
    const int kbase = g * 8;

    __shared__ __align__(16) float xs[NN*4];   // 4 KB
    __shared__ short aY[16*264];               // alpha*Y bf16, [msl][j] stride 264
    __shared__ float r_lds[NN];
    __shared__ float qs[CC];
    __shared__ float red[8];
    __shared__ float ssum_lds[LC];

    // ---- stage xs: 1 float4 per thread ----
    *(float4*)&xs[tid*4] = *(const float4*)&xg[(rowbase + tid)*4];
    __syncthreads();

    // ---- q_i (threads 0..31) ----
    if (tid < 32) {
        const float x0 = xs[i*4+0], x1 = xs[i*4+1], x2 = xs[i*4+2], x3 = xs[i*4+3];
        qs[tid] = x0*Wq[tid] + x1*Wq[32+tid] + x2*Wq[64+tid] + x3*Wq[96+tid];
    }
    __syncthreads();

    // ---- m[d] = sum_c q[c]*Wk[d][c] ----
    float m0 = 0.f, m1 = 0.f, m2 = 0.f, m3 = 0.f;
    #pragma unroll
    for (int c = 0; c < 32; ++c) {
        const float qc = qs[c];
        m0 += qc * Wk[c];
        m1 += qc * Wk[32+c];
        m2 += qc * Wk[64+c];
        m3 += qc * Wk[96+c];
    }
    const float lscale = 0.17677669529663687f;  // 1/sqrt(32)

    // ---- logit for j = tid; 4-wave softmax ----
    float lg;
    {
        const float4 xa = *(const float4*)&xs[tid*4];
        lg = (m0*xa.x + m1*xa.y + m2*xa.z + m3*xa.w) * lscale;
    }
    float mx = lg;
    #pragma unroll
    for (int off = 32; off >= 1; off >>= 1) mx = fmaxf(mx, __shfl_xor(mx, off));
    if (lane == 0) red[w] = mx;
    __syncthreads();
    mx = fmaxf(fmaxf(red[0], red[1]), fmaxf(red[2], red[3]));
    const float e = __expf(lg - mx);
    float s = e;
    #pragma unroll
    for (int off = 32; off >= 1; off >>= 1) s += __shfl_xor(s, off);
    if (lane == 0) red[4+w] = s;
    __syncthreads();
    const float alpha = e / (red[4] + red[5] + red[6] + red[7]);

    // ---- stage r and aY = alpha*Y (bf16) for j = tid ----
    const float cix = xs[i*4+0], ciy = xs[i*4+1], ciz = xs[i*4+2];
    {
        const int j = tid;
        const float4 xa = *(const float4*)&xs[j*4];
        const float dx = xa.x - cix, dy = xa.y - ciy, dz = xa.z - ciz;
        const float r2 = dx*dx + dy*dy + dz*dz + 1e-8f;
        r_lds[j] = sqrtf(r2);
        const float a = alpha;
        const float ir = rsqrtf(r2);
        const float ux = dx*ir, uy = dy*ir, uz = dz*ir;
        const float X2 = ux*ux, Y2 = uy*uy, Z2 = uz*uz;
        const float y0  = 0.28209479f;
        const float y1  = 0.48860251f*uy, y2 = 0.48860251f*uz, y3 = 0.48860251f*ux;
        const float y4  = 1.09254843f*ux*uy;
        const float y5  = 1.09254843f*uy*uz;
        const float y6  = 0.31539157f*(3.f*Z2 - 1.f);
        const float y7  = 1.09254843f*ux*uz;
        const float y8  = 0.54627422f*(X2 - Y2);
        const float y9  = 0.59004359f*uy*(3.f*X2 - Y2);
        const float y10 = 2.89061144f*ux*uy*uz;
        const float y11 = 0.45704579f*uy*(5.f*Z2 - 1.f);
        const float y12 = 0.37317633f*uz*(5.f*Z2 - 3.f);
        const float y13 = 0.45704579f*ux*(5.f*Z2 - 1.f);
        const float y14 = 1.44530572f*uz*(X2 - Y2);
        const float y15 = 0.59004359f*ux*(X2 - 3.f*Y2);
        #define ST2(mm, va, vb) { unsigned uu = pkbf((va)*a, (vb)*a); \
            aY[(mm)*264 + j] = (short)(uu & 0xffff); aY[(mm+1)*264 + j] = (short)(uu >> 16); }
        ST2(0,  y0,  y1)  ST2(2,  y2,  y3)
        ST2(4,  y4,  y5)  ST2(6,  y6,  y7)
        ST2(8,  y8,  y9)  ST2(10, y10, y11)
        ST2(12, y12, y13) ST2(14, y14, y15)
        #undef ST2
    }

    // ---- hoisted GEMM1 fragments (pre-packed weights) ----
    float rw1q[8], rb1q[8];
    #pragma unroll
    for (int q = 0; q < 8; ++q) { rw1q[q] = Rw1[kbase+q]; rb1q[q] = Rb1[kbase+q]; }

    short8 bfrag[4];
    f32x4 cinit[4];
    float4 wv[4];
    const int colbase = wcol * 64;
    #pragma unroll
    for (int t4 = 0; t4 < 4; ++t4) {
        const int col = colbase + t4*16 + n;
        bfrag[t4] = *(const short8*)&RW2bf[col*32 + kbase];
        const float rb = Rb2[col];
        cinit[t4] = (f32x4){rb, rb, rb, rb};
        wv[t4] = *(const float4*)&WvT[col*4];
    }

    const int boff = n*264 + 4*g;

    __syncthreads();   // aY + r_lds ready; loop is barrier-free

    f32x4 acc2[4] = {};

    #pragma unroll
    for (int tt = 0; tt < 4; ++tt) {
        const int j0 = jhalf*128 + tt*32;

        // ---- B2 fragment: aY[msl=n][j0+4g+e], e=0..3 and +16 rows ----
        const uint2 blo = *(const uint2*)&aY[boff + j0];
        const uint2 bhi = *(const uint2*)&aY[boff + j0 + 16];
        U8 bf2;
        bf2.u[0] = blo.x; bf2.u[1] = blo.y; bf2.u[2] = bhi.x; bf2.u[3] = bhi.y;

        // ---- GEMM1: G = (relu(r*Rw1+Rb1) @ Rw2 + Rb2) * v -> packed bf16 P ----
        uint2 P[2][4];
        #pragma unroll
        for (int jh = 0; jh < 2; ++jh) {
            const float rj = r_lds[(jhalf*8 + tt*2 + jh)*16 + n];
            U8 af;
            #pragma unroll
            for (int qq = 0; qq < 4; ++qq) {
                const float h0 = fmaxf(rj*rw1q[2*qq]   + rb1q[2*qq],   0.f);
                const float h1 = fmaxf(rj*rw1q[2*qq+1] + rb1q[2*qq+1], 0.f);
                af.u[qq] = pkbf(h0, h1);
            }
            float4 xv[4];
            #pragma unroll
            for (int e = 0; e < 4; ++e)
                xv[e] = *(const float4*)&xs[(j0 + jh*16 + 4*g + e)*4];
            #pragma unroll
            for (int t4 = 0; t4 < 4; ++t4) {
                f32x4 d = __builtin_amdgcn_mfma_f32_16x16x32_bf16(af.s, bfrag[t4], cinit[t4], 0, 0, 0);
                const float v0 = xv[0].x*wv[t4].x + xv[0].y*wv[t4].y + xv[0].z*wv[t4].z + xv[0].w*wv[t4].w;
                const float v1 = xv[1].x*wv[t4].x + xv[1].y*wv[t4].y + xv[1].z*wv[t4].z + xv[1].w*wv[t4].w;
                const float v2 = xv[2].x*wv[t4].x + xv[2].y*wv[t4].y + xv[2].z*wv[t4].z + xv[2].w*wv[t4].w;
                const float v3 = xv[3].x*wv[t4].x + xv[3].y*wv[t4].y + xv[3].z*wv[t4].z + xv[3].w*wv[t4].w;
                P[jh][t4].x = pkbf(d[0]*v0, d[1]*v1);
                P[jh][t4].y = pkbf(d[2]*v2, d[3]*v3);
            }
        }

        // ---- GEMM2: D[c][msl] += G^T @ aY (A from registers, shared B) ----
        #pragma unroll
        for (int t4 = 0; t4 < 4; ++t4) {
            U8 af2;
            af2.u[0] = P[0][t4].x; af2.u[1] = P[0][t4].y;
            af2.u[2] = P[1][t4].x; af2.u[3] = P[1][t4].y;
            acc2[t4] = __builtin_amdgcn_mfma_f32_16x16x32_bf16(af2.s, bf2.s, acc2[t4], 0, 0, 0);
        }
    }

    // ---- combine j-halves via LDS (alias aY), then square + msl-reduce ----
    __syncthreads();                        // all aY/r_lds reads complete
    float (*pacc)[128] = (float(*)[128])aY; // 16 x 128 x 4B = 8192 <= 8448
    if (jhalf == 0) {
        #pragma unroll
        for (int t4 = 0; t4 < 4; ++t4)
            #pragma unroll
            for (int q = 0; q < 4; ++q)
                pacc[t4*4 + q][wcol*64 + lane] = acc2[t4][q];
    }
    __syncthreads();
    if (jhalf == 1) {
        #pragma unroll
        for (int t4 = 0; t4 < 4; ++t4) {
            const int l = wcol*2 + (t4 >> 1);
            const int lo = l*l, hi = l*l + 2*l;
            const bool valid = (n >= lo) && (n <= hi);
            float s0 = acc2[t4][0] + pacc[t4*4+0][wcol*64 + lane];
            float s1 = acc2[t4][1] + pacc[t4*4+1][wcol*64 + lane];
            float s2 = acc2[t4][2] + pacc[t4*4+2][wcol*64 + lane];
            float s3 = acc2[t4][3] + pacc[t4*4+3][wcol*64 + lane];
            s0 = valid ? s0*s0 : 0.f;
            s1 = valid ? s1*s1 : 0.f;
            s2 = valid ? s2*s2 : 0.f;
            s3 = valid ? s3*s3 : 0.f;
            #pragma unroll
            for (int off = 1; off <= 8; off <<= 1) {
                s0 += __shfl_xor(s0, off);
                s1 += __shfl_xor(s1, off);
                s2 += __shfl_xor(s2, off);
                s3 += __shfl_xor(s3, off);
            }
            const float sv = (n==0) ? s0 : ((n==1) ? s1 : ((n==2) ? s2 : s3));
            if (n < 4) ssum_lds[colbase + t4*16 + g*4 + n] = sv;
        }
    }
    __syncthreads();
    if (tid < 128) {
        const float v = sqrtf(ssum_lds[tid] + 1e-8f);
        atomicMax((unsigned*)&pmaxg[b*LC + tid], __float_as_uint(v));
        atomicAdd(&psumg[b*LC + tid], v);
    }
}

// ---------------- Kernel C: fc1 + LN + relu + fc2 (pooled read) ----------------
__global__ __launch_bounds__(512) void so3_post(
    const float* __restrict__ pmaxg,  // (B,128)
    const float* __restrict__ psumg,  // (B,128)
    const float* __restrict__ fc1_w,  // (256,256)
    const float* __restrict__ fc1_b,  // (256)
    const float* __restrict__ ln_g,   // (256)
    const float* __restrict__ ln_b,   // (256)
    const float* __restrict__ fc2_w,  // (256,40)
    const float* __restrict__ fc2_b,  // (40)
    float* __restrict__ outg)         // (B,40)
{
    const int b = blockIdx.x;
    const int t = threadIdx.x;
    __shared__ float pooled[256];
    __shared__ float pfc1[2][256];
    __shared__ float h1s[256];
    __shared__ float pf2[8][40];
    __shared__ float redA[8], redB[8];

    if (t < 128)      pooled[t] = pmaxg[b*LC + t];
    else if (t < 256) pooled[t] = psumg[b*LC + (t-128)] * (1.f/256.f);
    __syncthreads();

    {
        const int o = t & 255, kh = t >> 8;
        float acc = 0.f;
        for (int k = kh*128; k < kh*128 + 128; ++k)
            acc += pooled[k] * fc1_w[k*256 + o];
        pfc1[kh][o] = acc;
    }
    __syncthreads();

    float hval = 0.f;
    if (t < 256) hval = pfc1[0][t] + pfc1[1][t] + fc1_b[t];

    const int lane = t & 63, wid = t >> 6;
    float s1 = hval, s2 = hval*hval;
    #pragma unroll
    for (int off = 32; off >= 1; off >>= 1) {
        s1 += __shfl_xor(s1, off);
        s2 += __shfl_xor(s2, off);
    }
    if (lane == 0) { redA[wid] = s1; redB[wid] = s2; }
    __syncthreads();
    s1 = redA[0]+redA[1]+redA[2]+redA[3];
    s2 = redB[0]+redB[1]+redB[2]+redB[3];
    if (t < 256) {
        const float mu = s1 * (1.f/256.f);
        const float var = s2 * (1.f/256.f) - mu*mu;
        float v = (hval - mu) * rsqrtf(var + 1e-5f) * ln_g[t] + ln_b[t];
        h1s[t] = fmaxf(v, 0.f);
    }
    __syncthreads();

    if (t < 320) {
        const int o = t % 40, ks = t / 40;
        float acc = 0.f;
        for (int k = ks*32; k < ks*32 + 32; ++k)
            acc += h1s[k] * fc2_w[k*40 + o];
        pf2[ks][o] = acc;
    }
    __syncthreads();
    if (t < 40) {
        float o = fc2_b[t];
        #pragma unroll
        for (int ks = 0; ks < 8; ++ks) o += pf2[ks][t];
        outg[b*40 + t] = o;
    }
}

extern "C" void kernel_launch(void* const* d_in, const int* in_sizes, int n_in,
                              void* d_out, int out_size, void* d_ws, size_t ws_size,
                              hipStream_t stream) {
    const float* x     = (const float*)d_in[0];
    const float* Wq    = (const float*)d_in[1];
    const float* Wk    = (const float*)d_in[2];
    const float* Wv    = (const float*)d_in[3];
    const float* Rw1   = (const float*)d_in[4];
    const float* Rb1   = (const float*)d_in[5];
    const float* Rw2   = (const float*)d_in[6];
    const float* Rb2   = (const float*)d_in[7];
    const float* fc1_w = (const float*)d_in[8];
    const float* fc1_b = (const float*)d_in[9];
    const float* ln_g  = (const float*)d_in[10];
    const float* ln_b  = (const float*)d_in[11];
    const float* fc2_w = (const float*)d_in[12];
    const float* fc2_b = (const float*)d_in[13];
    float* out = (float*)d_out;

    float* ws = (float*)d_ws;
    float* pmaxg = ws;                       // 1024 f32
    float* psumg = pmaxg + BB*LC;            // 1024 f32
    short* RW2bf = (short*)(psumg + BB*LC);  // 4096 bf16
    float* WvT   = (float*)(RW2bf + 4096);   // 512 f32

    so3_init<<<1, 256, 0, stream>>>(Rw2, Wv, pmaxg, psumg, RW2bf, WvT);
    so3_main<<<BN, 256, 0, stream>>>(x, Wq, Wk, Rw1, Rb1, RW2bf, Rb2, WvT, pmaxg, psumg);
    so3_post<<<BB, 512, 0, stream>>>(pmaxg, psumg, fc1_w, fc1_b, ln_g, ln_b, fc2_w, fc2_b, out);
}

// Round 12
// 48.479 us; speedup vs baseline: 1.7788x; 1.7788x over previous
//
#include <hip/hip_runtime.h>
#include <hip/hip_bf16.h>

#define BB 8
#define NN 256
#define CC 32
#define LL 4
#define BN (BB*NN)          // 2048
#define LC (LL*CC)          // 128

typedef short short8 __attribute__((ext_vector_type(8)));
typedef float f32x4 __attribute__((ext_vector_type(4)));

union U8 { short8 s; unsigned u[4]; };

__device__ inline unsigned pkbf(float a, float b){
    __hip_bfloat162 h = __float22bfloat162_rn(make_float2(a, b));
    union { __hip_bfloat162 h2; unsigned u; } cv; cv.h2 = h; return cv.u;
}

// ---------------- Kernel 0: init — zero pooled accumulators, pack Rw2/Wv ----------------
__global__ __launch_bounds__(256) void so3_init(
    const float* __restrict__ Rw2,    // (32,128)
    const float* __restrict__ Wv,     // (L,4,32)
    float* __restrict__ pmaxg,        // (B,128) -> 0
    float* __restrict__ psumg,        // (B,128) -> 0
    short* __restrict__ RW2bf,        // (128,32) bf16 [col][k]
    float* __restrict__ WvT)          // (128,4)  [col][d]
{
    const int t = threadIdx.x;
    #pragma unroll
    for (int rr = 0; rr < 4; ++rr) {
        pmaxg[rr*256 + t] = 0.f;
        psumg[rr*256 + t] = 0.f;
    }
    {
        const int col = t >> 1, kh = (t & 1) * 16;
        unsigned uu[8];
        #pragma unroll
        for (int q = 0; q < 8; ++q)
            uu[q] = pkbf(Rw2[(kh + 2*q)*LC + col], Rw2[(kh + 2*q + 1)*LC + col]);
        *(uint4*)&RW2bf[col*32 + kh]     = make_uint4(uu[0], uu[1], uu[2], uu[3]);
        *(uint4*)&RW2bf[col*32 + kh + 8] = make_uint4(uu[4], uu[5], uu[6], uu[7]);
    }
    if (t < 128) {
        const int l = t >> 5, c = t & 31;
        float4 o;
        o.x = Wv[l*128 +       c];
        o.y = Wv[l*128 +  32 + c];
        o.z = Wv[l*128 +  64 + c];
        o.w = Wv[l*128 +  96 + c];
        *(float4*)&WvT[t*4] = o;
    }
}

// ---------------- Kernel B: fused per-(b,i), 4 waves (col-half x j-half) ----------------
__global__ __launch_bounds__(256) void so3_main(
    const float* __restrict__ xg,     // (B,N,4)
    const float* __restrict__ Wq,     // (4,32)
    const float* __restrict__ Wk,     // (4,32)
    const float* __restrict__ Rw1,    // (32)
    const float* __restrict__ Rb1,    // (32)
    const short* __restrict__ RW2bf,  // (128,32) bf16
    const float* __restrict__ Rb2,    // (128)
    const float* __restrict__ WvT,    // (128,4)
    float* __restrict__ pmaxg,        // (B,128)
    float* __restrict__ psumg)        // (B,128)
{
    const int tid = threadIdx.x;          // 0..255
    const int bi = blockIdx.x;            // b*N + i
    const int b = bi >> 8;
    const int i = bi & 255;
    const int rowbase = b * NN;
    const int lane = tid & 63;
    const int w = tid >> 6;               // wave 0..3
    const int wcol = w & 1;               // column half
    const int jhalf = w >> 1;             // j half
    const int n = lane & 15;
    const int g = lane >> 4;
    const int kbase = g * 8;

    __shared__ __align__(16) float xs[NN*4];   // 4 KB
    __shared__ short aY[16*264];               // alpha*Y bf16, [msl][j] stride 264
    __shared__ float r_lds[NN];
    __shared__ float qs[CC];
    __shared__ float red[8];
    __shared__ float ssum_lds[LC];

    // ---- stage xs: 1 float4 per thread ----
    *(float4*)&xs[tid*4] = *(const float4*)&xg[(rowbase + tid)*4];
    __syncthreads();

    // ---- q_i (threads 0..31) ----
    if (tid < 32) {
        const float x0 = xs[i*4+0], x1 = xs[i*4+1], x2 = xs[i*4+2], x3 = xs[i*4+3];
        qs[tid] = x0*Wq[tid] + x1*Wq[32+tid] + x2*Wq[64+tid] + x3*Wq[96+tid];
    }
    __syncthreads();

    // ---- m[d] = sum_c q[c]*Wk[d][c] ----
    float m0 = 0.f, m1 = 0.f, m2 = 0.f, m3 = 0.f;
    #pragma unroll
    for (int c = 0; c < 32; ++c) {
        const float qc = qs[c];
        m0 += qc * Wk[c];
        m1 += qc * Wk[32+c];
        m2 += qc * Wk[64+c];
        m3 += qc * Wk[96+c];
    }
    const float lscale = 0.17677669529663687f;  // 1/sqrt(32)

    // ---- logit for j = tid; 4-wave softmax ----
    float lg;
    {
        const float4 xa = *(const float4*)&xs[tid*4];
        lg = (m0*xa.x + m1*xa.y + m2*xa.z + m3*xa.w) * lscale;
    }
    float mx = lg;
    #pragma unroll
    for (int off = 32; off >= 1; off >>= 1) mx = fmaxf(mx, __shfl_xor(mx, off));
    if (lane == 0) red[w] = mx;
    __syncthreads();
    mx = fmaxf(fmaxf(red[0], red[1]), fmaxf(red[2], red[3]));
    const float e = __expf(lg - mx);
    float s = e;
    #pragma unroll
    for (int off = 32; off >= 1; off >>= 1) s += __shfl_xor(s, off);
    if (lane == 0) red[4+w] = s;
    __syncthreads();
    const float alpha = e / (red[4] + red[5] + red[6] + red[7]);

    // ---- stage r and aY = alpha*Y (bf16) for j = tid ----
    const float cix = xs[i*4+0], ciy = xs[i*4+1], ciz = xs[i*4+2];
    {
        const int j = tid;
        const float4 xa = *(const float4*)&xs[j*4];
        const float dx = xa.x - cix, dy = xa.y - ciy, dz = xa.z - ciz;
        const float r2 = dx*dx + dy*dy + dz*dz + 1e-8f;
        r_lds[j] = sqrtf(r2);
        const float a = alpha;
        const float ir = rsqrtf(r2);
        const float ux = dx*ir, uy = dy*ir, uz = dz*ir;
        const float X2 = ux*ux, Y2 = uy*uy, Z2 = uz*uz;
        const float y0  = 0.28209479f;
        const float y1  = 0.48860251f*uy, y2 = 0.48860251f*uz, y3 = 0.48860251f*ux;
        const float y4  = 1.09254843f*ux*uy;
        const float y5  = 1.09254843f*uy*uz;
        const float y6  = 0.31539157f*(3.f*Z2 - 1.f);
        const float y7  = 1.09254843f*ux*uz;
        const float y8  = 0.54627422f*(X2 - Y2);
        const float y9  = 0.59004359f*uy*(3.f*X2 - Y2);
        const float y10 = 2.89061144f*ux*uy*uz;
        const float y11 = 0.45704579f*uy*(5.f*Z2 - 1.f);
        const float y12 = 0.37317633f*uz*(5.f*Z2 - 3.f);
        const float y13 = 0.45704579f*ux*(5.f*Z2 - 1.f);
        const float y14 = 1.44530572f*uz*(X2 - Y2);
        const float y15 = 0.59004359f*ux*(X2 - 3.f*Y2);
        #define ST2(mm, va, vb) { unsigned uu = pkbf((va)*a, (vb)*a); \
            aY[(mm)*264 + j] = (short)(uu & 0xffff); aY[(mm+1)*264 + j] = (short)(uu >> 16); }
        ST2(0,  y0,  y1)  ST2(2,  y2,  y3)
        ST2(4,  y4,  y5)  ST2(6,  y6,  y7)
        ST2(8,  y8,  y9)  ST2(10, y10, y11)
        ST2(12, y12, y13) ST2(14, y14, y15)
        #undef ST2
    }

    // ---- hoisted GEMM1 fragments (pre-packed weights) ----
    float rw1q[8], rb1q[8];
    #pragma unroll
    for (int q = 0; q < 8; ++q) { rw1q[q] = Rw1[kbase+q]; rb1q[q] = Rb1[kbase+q]; }

    short8 bfrag[4];
    f32x4 cinit[4];
    float4 wv[4];
    const int colbase = wcol * 64;
    #pragma unroll
    for (int t4 = 0; t4 < 4; ++t4) {
        const int col = colbase + t4*16 + n;
        bfrag[t4] = *(const short8*)&RW2bf[col*32 + kbase];
        const float rb = Rb2[col];
        cinit[t4] = (f32x4){rb, rb, rb, rb};
        wv[t4] = *(const float4*)&WvT[col*4];
    }

    const int boff = n*264 + 4*g;

    __syncthreads();   // aY + r_lds ready; loop is barrier-free

    f32x4 acc2[4] = {};

    #pragma unroll
    for (int tt = 0; tt < 4; ++tt) {
        const int j0 = jhalf*128 + tt*32;

        // ---- B2 fragment: aY[msl=n][j0+4g+e], e=0..3 and +16 rows ----
        const uint2 blo = *(const uint2*)&aY[boff + j0];
        const uint2 bhi = *(const uint2*)&aY[boff + j0 + 16];
        U8 bf2;
        bf2.u[0] = blo.x; bf2.u[1] = blo.y; bf2.u[2] = bhi.x; bf2.u[3] = bhi.y;

        // ---- GEMM1: G = (relu(r*Rw1+Rb1) @ Rw2 + Rb2) * v -> packed bf16 P ----
        uint2 P[2][4];
        #pragma unroll
        for (int jh = 0; jh < 2; ++jh) {
            const float rj = r_lds[(jhalf*8 + tt*2 + jh)*16 + n];
            U8 af;
            #pragma unroll
            for (int qq = 0; qq < 4; ++qq) {
                const float h0 = fmaxf(rj*rw1q[2*qq]   + rb1q[2*qq],   0.f);
                const float h1 = fmaxf(rj*rw1q[2*qq+1] + rb1q[2*qq+1], 0.f);
                af.u[qq] = pkbf(h0, h1);
            }
            float4 xv[4];
            #pragma unroll
            for (int e = 0; e < 4; ++e)
                xv[e] = *(const float4*)&xs[(j0 + jh*16 + 4*g + e)*4];
            #pragma unroll
            for (int t4 = 0; t4 < 4; ++t4) {
                f32x4 d = __builtin_amdgcn_mfma_f32_16x16x32_bf16(af.s, bfrag[t4], cinit[t4], 0, 0, 0);
                const float v0 = xv[0].x*wv[t4].x + xv[0].y*wv[t4].y + xv[0].z*wv[t4].z + xv[0].w*wv[t4].w;
                const float v1 = xv[1].x*wv[t4].x + xv[1].y*wv[t4].y + xv[1].z*wv[t4].z + xv[1].w*wv[t4].w;
                const float v2 = xv[2].x*wv[t4].x + xv[2].y*wv[t4].y + xv[2].z*wv[t4].z + xv[2].w*wv[t4].w;
                const float v3 = xv[3].x*wv[t4].x + xv[3].y*wv[t4].y + xv[3].z*wv[t4].z + xv[3].w*wv[t4].w;
                P[jh][t4].x = pkbf(d[0]*v0, d[1]*v1);
                P[jh][t4].y = pkbf(d[2]*v2, d[3]*v3);
            }
        }

        // ---- GEMM2: D[c][msl] += G^T @ aY (A from registers, shared B) ----
        #pragma unroll
        for (int t4 = 0; t4 < 4; ++t4) {
            U8 af2;
            af2.u[0] = P[0][t4].x; af2.u[1] = P[0][t4].y;
            af2.u[2] = P[1][t4].x; af2.u[3] = P[1][t4].y;
            acc2[t4] = __builtin_amdgcn_mfma_f32_16x16x32_bf16(af2.s, bf2.s, acc2[t4], 0, 0, 0);
        }
    }

    // ---- combine j-halves via LDS (alias aY), then square + msl-reduce ----
    __syncthreads();                        // all aY/r_lds reads complete
    float (*pacc)[128] = (float(*)[128])aY; // 16 x 128 x 4B = 8192 <= 8448
    if (jhalf == 0) {
        #pragma unroll
        for (int t4 = 0; t4 < 4; ++t4)
            #pragma unroll
            for (int q = 0; q < 4; ++q)
                pacc[t4*4 + q][wcol*64 + lane] = acc2[t4][q];
    }
    __syncthreads();
    if (jhalf == 1) {
        #pragma unroll
        for (int t4 = 0; t4 < 4; ++t4) {
            const int l = wcol*2 + (t4 >> 1);
            const int lo = l*l, hi = l*l + 2*l;
            const bool valid = (n >= lo) && (n <= hi);
            float s0 = acc2[t4][0] + pacc[t4*4+0][wcol*64 + lane];
            float s1 = acc2[t4][1] + pacc[t4*4+1][wcol*64 + lane];
            float s2 = acc2[t4][2] + pacc[t4*4+2][wcol*64 + lane];
            float s3 = acc2[t4][3] + pacc[t4*4+3][wcol*64 + lane];
            s0 = valid ? s0*s0 : 0.f;
            s1 = valid ? s1*s1 : 0.f;
            s2 = valid ? s2*s2 : 0.f;
            s3 = valid ? s3*s3 : 0.f;
            #pragma unroll
            for (int off = 1; off <= 8; off <<= 1) {
                s0 += __shfl_xor(s0, off);
                s1 += __shfl_xor(s1, off);
                s2 += __shfl_xor(s2, off);
                s3 += __shfl_xor(s3, off);
            }
            const float sv = (n==0) ? s0 : ((n==1) ? s1 : ((n==2) ? s2 : s3));
            if (n < 4) ssum_lds[colbase + t4*16 + g*4 + n] = sv;
        }
    }
    __syncthreads();
    if (tid < 128) {
        const float v = sqrtf(ssum_lds[tid] + 1e-8f);
        atomicMax((unsigned*)&pmaxg[b*LC + tid], __float_as_uint(v));
        atomicAdd(&psumg[b*LC + tid], v);
    }
}

// ---------------- Kernel C: fc1 + LN + relu + fc2 (pooled read) ----------------
__global__ __launch_bounds__(512) void so3_post(
    const float* __restrict__ pmaxg,  // (B,128)
    const float* __restrict__ psumg,  // (B,128)
    const float* __restrict__ fc1_w,  // (256,256)
    const float* __restrict__ fc1_b,  // (256)
    const float* __restrict__ ln_g,   // (256)
    const float* __restrict__ ln_b,   // (256)
    const float* __restrict__ fc2_w,  // (256,40)
    const float* __restrict__ fc2_b,  // (40)
    float* __restrict__ outg)         // (B,40)
{
    const int b = blockIdx.x;
    const int t = threadIdx.x;
    __shared__ float pooled[256];
    __shared__ float pfc1[2][256];
    __shared__ float h1s[256];
    __shared__ float pf2[8][40];
    __shared__ float redA[8], redB[8];

    if (t < 128)      pooled[t] = pmaxg[b*LC + t];
    else if (t < 256) pooled[t] = psumg[b*LC + (t-128)] * (1.f/256.f);
    __syncthreads();

    {
        const int o = t & 255, kh = t >> 8;
        float acc = 0.f;
        for (int k = kh*128; k < kh*128 + 128; ++k)
            acc += pooled[k] * fc1_w[k*256 + o];
        pfc1[kh][o] = acc;
    }
    __syncthreads();

    float hval = 0.f;
    if (t < 256) hval = pfc1[0][t] + pfc1[1][t] + fc1_b[t];

    const int lane = t & 63, wid = t >> 6;
    float s1 = hval, s2 = hval*hval;
    #pragma unroll
    for (int off = 32; off >= 1; off >>= 1) {
        s1 += __shfl_xor(s1, off);
        s2 += __shfl_xor(s2, off);
    }
    if (lane == 0) { redA[wid] = s1; redB[wid] = s2; }
    __syncthreads();
    s1 = redA[0]+redA[1]+redA[2]+redA[3];
    s2 = redB[0]+redB[1]+redB[2]+redB[3];
    if (t < 256) {
        const float mu = s1 * (1.f/256.f);
        const float var = s2 * (1.f/256.f) - mu*mu;
        float v = (hval - mu) * rsqrtf(var + 1e-5f) * ln_g[t] + ln_b[t];
        h1s[t] = fmaxf(v, 0.f);
    }
    __syncthreads();

    if (t < 320) {
        const int o = t % 40, ks = t / 40;
        float acc = 0.f;
        for (int k = ks*32; k < ks*32 + 32; ++k)
            acc += h1s[k] * fc2_w[k*40 + o];
        pf2[ks][o] = acc;
    }
    __syncthreads();
    if (t < 40) {
        float o = fc2_b[t];
        #pragma unroll
        for (int ks = 0; ks < 8; ++ks) o += pf2[ks][t];
        outg[b*40 + t] = o;
    }
}

extern "C" void kernel_launch(void* const* d_in, const int* in_sizes, int n_in,
                              void* d_out, int out_size, void* d_ws, size_t ws_size,
                              hipStream_t stream) {
    const float* x     = (const float*)d_in[0];
    const float* Wq    = (const float*)d_in[1];
    const float* Wk    = (const float*)d_in[2];
    const float* Wv    = (const float*)d_in[3];
    const float* Rw1   = (const float*)d_in[4];
    const float* Rb1   = (const float*)d_in[5];
    const float* Rw2   = (const float*)d_in[6];
    const float* Rb2   = (const float*)d_in[7];
    const float* fc1_w = (const float*)d_in[8];
    const float* fc1_b = (const float*)d_in[9];
    const float* ln_g  = (const float*)d_in[10];
    const float* ln_b  = (const float*)d_in[11];
    const float* fc2_w = (const float*)d_in[12];
    const float* fc2_b = (const float*)d_in[13];
    float* out = (float*)d_out;

    float* ws = (float*)d_ws;
    float* pmaxg = ws;                       // 1024 f32
    float* psumg = pmaxg + BB*LC;            // 1024 f32
    short* RW2bf = (short*)(psumg + BB*LC);  // 4096 bf16
    float* WvT   = (float*)(RW2bf + 4096);   // 512 f32

    so3_init<<<1, 256, 0, stream>>>(Rw2, Wv, pmaxg, psumg, RW2bf, WvT);
    so3_main<<<BN, 256, 0, stream>>>(x, Wq, Wk, Rw1, Rb1, RW2bf, Rb2, WvT, pmaxg, psumg);
    so3_post<<<BB, 512, 0, stream>>>(pmaxg, psumg, fc1_w, fc1_b, ln_g, ln_b, fc2_w, fc2_b, out);
}